// Round 1
// baseline (446.997 us; speedup 1.0000x reference)
//
#include <hip/hip_runtime.h>

// Problem constants (fixed by the reference)
constexpr int Bc  = 4;
constexpr int Lc  = 2048;
constexpr int Dc  = 8192;
constexpr int QKc = 2048;
constexpr int Vc  = 4096;
constexpr int TCH = 64;          // timesteps per thread
constexpr int NCH = Lc / TCH;    // 32 chunks
constexpr int D4  = Dc / 4;      // 2048 float4 channel groups

// Output layout offsets in float4 units: q | k | v | new_cache
constexpr size_t K_OFF4 = (size_t)Bc * Lc * QKc / 4;            // 4,194,304
constexpr size_t V_OFF4 = 2 * K_OFF4;                           // 8,388,608
constexpr size_t C_OFF4 = V_OFF4 + (size_t)Bc * Lc * Vc / 4;    // 16,777,216

__global__ __launch_bounds__(256)
void qkvconv_kernel(const float4* __restrict__ x4,
                    const float4* __restrict__ cache4,
                    const float4* __restrict__ w4,
                    float4* __restrict__ out4)
{
    const int gid   = blockIdx.x * blockDim.x + threadIdx.x;
    const int dg    = gid & (D4 - 1);      // float4 channel group
    const int rest  = gid >> 11;
    const int chunk = rest & (NCH - 1);
    const int b     = rest >> 5;

    const int d  = dg << 2;                // first channel of this thread
    const int t0 = chunk * TCH;

    // weight rows are naturally float4 (K=4): wr_i = taps for channel d+i
    const float4 wr0 = w4[d + 0];
    const float4 wr1 = w4[d + 1];
    const float4 wr2 = w4[d + 2];
    const float4 wr3 = w4[d + 3];

    const size_t xbase = ((size_t)b * Lc) * D4 + dg;

    // rolling history: h0 = x[t-3], h1 = x[t-2], h2 = x[t-1] (per channel)
    float4 h0, h1, h2;
    if (t0 == 0) {
        // cache row per channel is float4; taps 1..3 are the causal history
        const float4 c0 = cache4[(size_t)b * Dc + d + 0];
        const float4 c1 = cache4[(size_t)b * Dc + d + 1];
        const float4 c2 = cache4[(size_t)b * Dc + d + 2];
        const float4 c3 = cache4[(size_t)b * Dc + d + 3];
        h0 = make_float4(c0.y, c1.y, c2.y, c3.y);
        h1 = make_float4(c0.z, c1.z, c2.z, c3.z);
        h2 = make_float4(c0.w, c1.w, c2.w, c3.w);
    } else {
        h0 = x4[xbase + (size_t)(t0 - 3) * D4];
        h1 = x4[xbase + (size_t)(t0 - 2) * D4];
        h2 = x4[xbase + (size_t)(t0 - 1) * D4];
    }

    // output base (float4 units) + per-timestep stride, by q/k/v segment
    size_t obase;
    int    ostride;
    if (d < QKc) {
        obase   = ((size_t)b * Lc) * (QKc / 4) + dg;
        ostride = QKc / 4;
    } else if (d < 2 * QKc) {
        obase   = K_OFF4 + ((size_t)b * Lc) * (QKc / 4) + (dg - QKc / 4);
        ostride = QKc / 4;
    } else {
        obase   = V_OFF4 + ((size_t)b * Lc) * (Vc / 4) + (dg - 2 * QKc / 4);
        ostride = Vc / 4;
    }

    #pragma unroll 8
    for (int t = t0; t < t0 + TCH; ++t) {
        const float4 cur = x4[xbase + (size_t)t * D4];
        float4 y;
        y.x = wr0.x * h0.x + wr0.y * h1.x + wr0.z * h2.x + wr0.w * cur.x;
        y.y = wr1.x * h0.y + wr1.y * h1.y + wr1.z * h2.y + wr1.w * cur.y;
        y.z = wr2.x * h0.z + wr2.y * h1.z + wr2.z * h2.z + wr2.w * cur.z;
        y.w = wr3.x * h0.w + wr3.y * h1.w + wr3.z * h2.w + wr3.w * cur.w;
        // silu
        y.x = y.x / (1.0f + __expf(-y.x));
        y.y = y.y / (1.0f + __expf(-y.y));
        y.z = y.z / (1.0f + __expf(-y.z));
        y.w = y.w / (1.0f + __expf(-y.w));
        out4[obase + (size_t)t * ostride] = y;
        h0 = h1; h1 = h2; h2 = cur;
    }

    // last chunk writes new_cache[b, d, 0..3] = x[b, L-4 .. L-1, d]
    if (chunk == NCH - 1) {
        const float4 xm4 = x4[xbase + (size_t)(Lc - 4) * D4];
        // after loop: h0 = x[L-3], h1 = x[L-2], h2 = x[L-1]
        out4[C_OFF4 + (size_t)b * Dc + d + 0] = make_float4(xm4.x, h0.x, h1.x, h2.x);
        out4[C_OFF4 + (size_t)b * Dc + d + 1] = make_float4(xm4.y, h0.y, h1.y, h2.y);
        out4[C_OFF4 + (size_t)b * Dc + d + 2] = make_float4(xm4.z, h0.z, h1.z, h2.z);
        out4[C_OFF4 + (size_t)b * Dc + d + 3] = make_float4(xm4.w, h0.w, h1.w, h2.w);
    }
}

extern "C" void kernel_launch(void* const* d_in, const int* in_sizes, int n_in,
                              void* d_out, int out_size, void* d_ws, size_t ws_size,
                              hipStream_t stream) {
    const float4* x4     = (const float4*)d_in[0];   // (B, L, D) fp32
    const float4* cache4 = (const float4*)d_in[1];   // (B, D, K) fp32
    const float4* w4     = (const float4*)d_in[2];   // (D, K) fp32
    float4* out4 = (float4*)d_out;                   // q|k|v|new_cache fp32

    const int total  = Bc * NCH * D4;                // 262,144 threads
    const int block  = 256;
    qkvconv_kernel<<<total / block, block, 0, stream>>>(x4, cache4, w4, out4);
}